// Round 5
// baseline (20867.052 us; speedup 1.0000x reference)
//
#include <hip/hip_runtime.h>
#include <hip/hip_cooperative_groups.h>

namespace cg = cooperative_groups;

#define T_DIM 512
#define B_DIM 64
#define H_DIM 1024
#define NQP 272                 // k-quads per gate, padded (256 real + 16 zero)
#define GSTR ((size_t)NQP * H_DIM)   // float4 per gate

// ws layout (floats):
//   Wv   [6][NQP][H][4]  masked, k-quad-interleaved, zero-padded quads 256..271:
//                        Wv[g][kq][j][u] = (k=4kq+u; k<1024 && k>=j) ? W_g[k][j] : 0
//   hbuf [2][B][H]       hidden ping-pong
//   pmax [T][B][16]      per-pair label maxes

// ---------------- prep: mask + k-quad interleave + zero pad ----------------
__global__ __launch_bounds__(256) void prep_interleave(
    const float* __restrict__ Wir, const float* __restrict__ Wiz, const float* __restrict__ Win,
    const float* __restrict__ Whr, const float* __restrict__ Whz, const float* __restrict__ Whn,
    float* __restrict__ Wv)
{
    const float* srcs[6] = {Wir, Wiz, Win, Whr, Whz, Whn};
    const int kq = blockIdx.x;                    // 0..271
    const int j  = blockIdx.y * 256 + threadIdx.x;
    const int g  = blockIdx.z;
    const float* src = srcs[g];
    float tmp[4];
    #pragma unroll
    for (int u = 0; u < 4; ++u) {
        const int k = 4 * kq + u;
        float w = 0.0f;
        if (k < H_DIM) {                          // pad quads read nothing
            w = src[(size_t)k * H_DIM + j];
            if (k < j) w = 0.0f;                  // tril mask
        }
        tmp[u] = w;
    }
    float4* dst = (float4*)Wv + ((size_t)g * NQP + kq) * H_DIM + j;
    *dst = make_float4(tmp[0], tmp[1], tmp[2], tmp[3]);
}

__global__ __launch_bounds__(256) void init_h(const float* __restrict__ h0, float* __restrict__ hbuf)
{
    const int i = blockIdx.x * 256 + threadIdx.x;
    if (i < B_DIM * H_DIM) hbuf[i] = h0[i];
}

// ---------------- main: 256 WGs x 512 threads, 1 grid.sync/step ----------------
// 32 column blocks of 32; pair i = blocks (i, 31-i), uniform 1056 k-rows. 16 pairs x
// 16 bgroups (4 b rows) = 256 WGs. Lane = (jl = lane&31 column, sk = lane>>5 k-slot);
// 8 waves x 2 half-waves split each block's quads; register-prefetched weight stream.
__global__ __launch_bounds__(512, 1) void gru_main(
    const float* __restrict__ x,      // [T,B,H]
    const float* __restrict__ Wv,     // [6,NQP,H,4]
    const float* __restrict__ bir, const float* __restrict__ bhr,
    const float* __restrict__ biz, const float* __restrict__ bhz,
    const float* __restrict__ bin_, const float* __restrict__ bhn,
    const float* __restrict__ Wout, const float* __restrict__ bout,
    float* __restrict__ hbuf,         // [2,B,H]
    float* __restrict__ pmax)         // [T,B,16]
{
    cg::grid_group grid = cg::this_grid();

    __shared__ float4 sxh[NQP][9];    // [kq_rel][c] c<4: x rows, c 4..7: h rows; [8]=bank pad
    __shared__ float4 red[8][4][32];  // [wave][b][jl] folded partials (r,z,ni,nh)
    __shared__ float  mxs[4][2];      // [b][blk] label maxes

    const int tid  = threadIdx.x;
    const int lane = tid & 63;
    const int jl   = lane & 31;       // column within 32-block
    const int sk   = lane >> 5;       // k parity
    const int ww   = tid >> 6;        // 0..7

    const int xcd  = blockIdx.x & 7;
    const int slot = blockIdx.x >> 3;
    const int pair = xcd + 8 * (slot & 1);   // 0..15; 2 pairs per XCD
    const int bg   = slot >> 1;              // 0..15
    const int b0   = bg * 4;

    const int jA0 = 32 * pair,        QA = 8 * pair,        CA = 256 - 8 * pair;
    const int jB0 = 32 * (31 - pair), QB = 248 - 8 * pair,  CB = 8 * pair + 8;
    const int QPHA = (CA + 15) >> 4;
    const int QPHB = (CB + 15) >> 4;
    const int kq0 = QA;                      // staged quad origin
    const int nq  = 256 - 8 * pair;          // real staged quads

    // epilogue per-thread constants (b = tid>>5, jl) for both column blocks
    const int jA = jA0 + (tid & 31), jB = jB0 + (tid & 31);
    const float bo = bout[0];
    const float cA_bir = bir[jA], cA_bhr = bhr[jA], cA_biz = biz[jA], cA_bhz = bhz[jA];
    const float cA_bin = bin_[jA], cA_bhn = bhn[jA], cA_wo = Wout[jA];
    const float cB_bir = bir[jB], cB_bhr = bhr[jB], cB_biz = biz[jB], cB_bhz = bhz[jB];
    const float cB_bin = bin_[jB], cB_bhn = bhn[jB], cB_wo = Wout[jB];

    const float4* Wv4 = (const float4*)Wv;

    // zero all of sxh once: pad rows (>= nq) must stay zero (masked weights hit them)
    for (int i = tid; i < NQP * 9; i += 512) ((float4*)sxh)[i] = make_float4(0.f, 0.f, 0.f, 0.f);
    __syncthreads();

    for (int t = 0; t < T_DIM; ++t) {
        const float* hid  = hbuf + (size_t)(t & 1) * (B_DIM * H_DIM);
        float*       hidn = hbuf + (size_t)((t + 1) & 1) * (B_DIM * H_DIM);
        const float* xt   = x + (size_t)t * (B_DIM * H_DIM);

        // ---- stage x,h (4 rows each) into quad-major layout ----
        {
            const int c = tid >> 6;                       // 0..7
            const int b = b0 + (c & 3);
            const float* src = (c < 4 ? xt : hid) + (size_t)b * H_DIM;
            #pragma unroll
            for (int r = 0; r < 4; ++r) {
                const int kq = (tid & 63) + (r << 6);     // 0..255, coalesced
                if (kq < nq)
                    sxh[kq][c] = *(const float4*)(src + 4 * (kq0 + kq));
            }
        }
        __syncthreads();

        #pragma unroll
        for (int bl = 0; bl < 2; ++bl) {
            const int j0  = bl ? jB0 : jA0;
            const int Qs  = bl ? QB : QA;
            const int QPH = bl ? QPHB : QPHA;
            const int qb  = Qs + 2 * ww * QPH;            // wave's quad base

            const float4* g0 = Wv4 + 0 * GSTR + j0 + jl;  // ir
            const float4* g1 = Wv4 + 1 * GSTR + j0 + jl;  // iz
            const float4* g2 = Wv4 + 2 * GSTR + j0 + jl;  // in
            const float4* g3 = Wv4 + 3 * GSTR + j0 + jl;  // hr
            const float4* g4 = Wv4 + 4 * GSTR + j0 + jl;  // hz
            const float4* g5 = Wv4 + 5 * GSTR + j0 + jl;  // hn

            float4 acc[4];
            #pragma unroll
            for (int i = 0; i < 4; ++i) acc[i] = make_float4(0.f, 0.f, 0.f, 0.f);

            size_t qi = (size_t)(qb + sk) * H_DIM;        // float4 index offset
            int row = qb + sk - kq0;
            float4 cw0 = g0[qi], cw1 = g1[qi], cw2 = g2[qi],
                   cw3 = g3[qi], cw4 = g4[qi], cw5 = g5[qi];

            for (int iq = 0; iq < QPH; ++iq) {
                const size_t qn = qi + 2 * H_DIM;         // next (prefetch; pad-safe)
                const float4 nw0 = g0[qn], nw1 = g1[qn], nw2 = g2[qn],
                             nw3 = g3[qn], nw4 = g4[qn], nw5 = g5[qn];
                #pragma unroll
                for (int b = 0; b < 4; ++b) {
                    const float4 xv = sxh[row][b];        // 2-addr broadcast (free)
                    const float4 hv = sxh[row][4 + b];
#define ACC(c) \
                    acc[b].x = fmaf(xv.c, cw0.c, fmaf(hv.c, cw3.c, acc[b].x)); \
                    acc[b].y = fmaf(xv.c, cw1.c, fmaf(hv.c, cw4.c, acc[b].y)); \
                    acc[b].z = fmaf(xv.c, cw2.c, acc[b].z); \
                    acc[b].w = fmaf(hv.c, cw5.c, acc[b].w);
                    ACC(x) ACC(y) ACC(z) ACC(w)
#undef ACC
                }
                cw0 = nw0; cw1 = nw1; cw2 = nw2; cw3 = nw3; cw4 = nw4; cw5 = nw5;
                qi = qn; row += 2;
            }

            // ---- fold sk halves in-register, write per-wave partials ----
            #pragma unroll
            for (int b = 0; b < 4; ++b) {
                acc[b].x += __shfl_xor(acc[b].x, 32);
                acc[b].y += __shfl_xor(acc[b].y, 32);
                acc[b].z += __shfl_xor(acc[b].z, 32);
                acc[b].w += __shfl_xor(acc[b].w, 32);
            }
            if (lane < 32) {
                #pragma unroll
                for (int b = 0; b < 4; ++b) red[ww][b][jl] = acc[b];
            }
            __syncthreads();

            // ---- waves 0-1: reduce 8 waves, gates, h-write, label max ----
            if (tid < 128) {
                const int b   = tid >> 5;
                const int jl2 = tid & 31;
                const int j   = j0 + jl2;
                float4 s = red[0][b][jl2];
                #pragma unroll
                for (int w2 = 1; w2 < 8; ++w2) {
                    const float4 v = red[w2][b][jl2];
                    s.x += v.x; s.y += v.y; s.z += v.z; s.w += v.w;
                }
                const int rr = bl ? (248 - 16 * pair + (jl2 >> 2)) : (jl2 >> 2);
                const float4 xq = sxh[rr][b];
                const float4 hq = sxh[rr][4 + b];
                const float xv = ((const float*)&xq)[jl2 & 3];
                const float hv = ((const float*)&hq)[jl2 & 3];
                const float v_bir = bl ? cB_bir : cA_bir, v_bhr = bl ? cB_bhr : cA_bhr;
                const float v_biz = bl ? cB_biz : cA_biz, v_bhz = bl ? cB_bhz : cA_bhz;
                const float v_bin = bl ? cB_bin : cA_bin, v_bhn = bl ? cB_bhn : cA_bhn;
                const float v_wo  = bl ? cB_wo  : cA_wo;
                const float rp = s.x + v_bir * xv + v_bhr;
                const float zp = s.y + v_biz * xv + v_bhz;
                const float r  = 1.0f / (1.0f + expf(-rp));
                const float z  = 1.0f / (1.0f + expf(-zp));
                const float np = s.z + v_bin * xv + r * (s.w + v_bhn);
                const float n  = tanhf(np);
                const float hnew = hv * z + (1.0f - z) * n;
                hidn[(size_t)(b0 + b) * H_DIM + j] = hnew;
                float lab = (1.0f / (1.0f + expf(-(hnew * v_wo + bo)))) * xv;
                #pragma unroll
                for (int off = 16; off; off >>= 1)
                    lab = fmaxf(lab, __shfl_xor(lab, off));
                if ((tid & 31) == 0) mxs[b][bl] = lab;
            }
            __syncthreads();   // red free for next blk; mxs visible
        }

        if (tid < 4)
            pmax[((size_t)t * B_DIM + b0 + tid) * 16 + pair] = fmaxf(mxs[tid][0], mxs[tid][1]);

        grid.sync();           // h(t+1) visible device-wide
    }
}

// ---------------- finalize ----------------
__global__ __launch_bounds__(256) void finalize(const float* __restrict__ pmax, int* __restrict__ out)
{
    const int i = blockIdx.x * 256 + threadIdx.x; // 0..T*B-1
    if (i >= T_DIM * B_DIM) return;
    const float4* pm = (const float4*)(pmax + (size_t)i * 16);
    float m = -3.4e38f;
    #pragma unroll
    for (int q = 0; q < 4; ++q) {
        const float4 v = pm[q];
        m = fmaxf(m, fmaxf(fmaxf(v.x, v.y), fmaxf(v.z, v.w)));
    }
    out[i] = (m >= 0.5f) ? 1 : -1;
}

extern "C" void kernel_launch(void* const* d_in, const int* in_sizes, int n_in,
                              void* d_out, int out_size, void* d_ws, size_t ws_size,
                              hipStream_t stream)
{
    const float* x    = (const float*)d_in[0];
    const float* h0   = (const float*)d_in[1];
    const float* W_ir = (const float*)d_in[2];
    const float* W_hr = (const float*)d_in[3];
    const float* W_iz = (const float*)d_in[4];
    const float* W_hz = (const float*)d_in[5];
    const float* W_in = (const float*)d_in[6];
    const float* W_hn = (const float*)d_in[7];
    const float* b_ir = (const float*)d_in[8];
    const float* b_hr = (const float*)d_in[9];
    const float* b_iz = (const float*)d_in[10];
    const float* b_hz = (const float*)d_in[11];
    const float* b_in = (const float*)d_in[12];
    const float* b_hn = (const float*)d_in[13];
    const float* W_out = (const float*)d_in[14];
    const float* b_out = (const float*)d_in[15];

    float* ws   = (float*)d_ws;
    float* Wv   = ws;                                        // 6*NQP*H*4 floats (~26.7 MB)
    float* hbuf = Wv + (size_t)6 * NQP * H_DIM * 4;          // 2*B*H
    float* pmax = hbuf + (size_t)2 * B_DIM * H_DIM;          // T*B*16 (2 MB)

    prep_interleave<<<dim3(NQP, 4, 6), 256, 0, stream>>>(W_ir, W_iz, W_in, W_hr, W_hz, W_hn, Wv);
    init_h<<<dim3(256), 256, 0, stream>>>(h0, hbuf);

    void* args[] = {(void*)&x, (void*)&Wv,
                    (void*)&b_ir, (void*)&b_hr, (void*)&b_iz, (void*)&b_hz,
                    (void*)&b_in, (void*)&b_hn, (void*)&W_out, (void*)&b_out,
                    (void*)&hbuf, (void*)&pmax};
    hipLaunchCooperativeKernel((const void*)gru_main, dim3(256), dim3(512), args, 0, stream);

    finalize<<<dim3(T_DIM * B_DIM / 256), 256, 0, stream>>>(pmax, (int*)d_out);
}

// Round 6
// 9584.328 us; speedup vs baseline: 2.1772x; 2.1772x over previous
//
#include <hip/hip_runtime.h>

#define T_DIM 512
#define B_DIM 64
#define H_DIM 1024
#define NQP 272                 // k-quads per gate, padded (256 real + 16 zero)
#define GSTR ((size_t)NQP * H_DIM)   // float4 per gate

// ws layout (floats):
//   Wv   [6][NQP][H][4]  masked, k-quad-interleaved, zero-padded quads 256..271
//   hbuf [2][B][H]       hidden ping-pong (device-coherent via agent-scope ops)
//   pmax [T][B][16]      per-pair label maxes
//   barc [16][64]        per-bgroup monotone barrier counters (256B apart)

// ---------------- prep: mask + k-quad interleave + zero pad ----------------
__global__ __launch_bounds__(256) void prep_interleave(
    const float* __restrict__ Wir, const float* __restrict__ Wiz, const float* __restrict__ Win,
    const float* __restrict__ Whr, const float* __restrict__ Whz, const float* __restrict__ Whn,
    float* __restrict__ Wv)
{
    const float* srcs[6] = {Wir, Wiz, Win, Whr, Whz, Whn};
    const int kq = blockIdx.x;                    // 0..271
    const int j  = blockIdx.y * 256 + threadIdx.x;
    const int g  = blockIdx.z;
    const float* src = srcs[g];
    float tmp[4];
    #pragma unroll
    for (int u = 0; u < 4; ++u) {
        const int k = 4 * kq + u;
        float w = 0.0f;
        if (k < H_DIM) {
            w = src[(size_t)k * H_DIM + j];
            if (k < j) w = 0.0f;                  // tril mask
        }
        tmp[u] = w;
    }
    float4* dst = (float4*)Wv + ((size_t)g * NQP + kq) * H_DIM + j;
    *dst = make_float4(tmp[0], tmp[1], tmp[2], tmp[3]);
}

__global__ __launch_bounds__(256) void init_h(const float* __restrict__ h0,
                                              float* __restrict__ hbuf,
                                              unsigned* __restrict__ barc)
{
    if (blockIdx.x < 256) {
        const int i = blockIdx.x * 256 + threadIdx.x;
        if (i < B_DIM * H_DIM) hbuf[i] = h0[i];
    } else {
        #pragma unroll
        for (int k = 0; k < 4; ++k) barc[threadIdx.x + 256 * k] = 0u;
    }
}

// ---------------- main: 256 WGs x 512 threads, per-bgroup 16-WG barriers ----------------
// Structure identical to round 5 except: grid.sync() -> per-bgroup monotone barrier;
// h reads/writes are agent-scope (coherence point), weights/x are normal loads so the
// per-XCD L2 weight slice stays resident across all 512 steps (never invalidated).
__global__ __launch_bounds__(512, 1) void gru_main(
    const float* __restrict__ x,      // [T,B,H]
    const float* __restrict__ Wv,     // [6,NQP,H,4]
    const float* __restrict__ bir, const float* __restrict__ bhr,
    const float* __restrict__ biz, const float* __restrict__ bhz,
    const float* __restrict__ bin_, const float* __restrict__ bhn,
    const float* __restrict__ Wout, const float* __restrict__ bout,
    float* __restrict__ hbuf,         // [2,B,H]
    float* __restrict__ pmax,         // [T,B,16]
    unsigned* __restrict__ barc)      // [16][64]
{
    __shared__ float4 sxh[NQP][9];    // [kq_rel][c] c<4: x rows, c 4..7: h rows; [8]=bank pad
    __shared__ float4 red[8][4][32];  // [wave][b][jl] folded partials (r,z,ni,nh)
    __shared__ float  mxs[4][2];      // [b][blk] label maxes

    const int tid  = threadIdx.x;
    const int lane = tid & 63;
    const int jl   = lane & 31;       // column within 32-block
    const int sk   = lane >> 5;       // k parity
    const int ww   = tid >> 6;        // 0..7

    const int xcd  = blockIdx.x & 7;
    const int slot = blockIdx.x >> 3;
    const int pair = xcd + 8 * (slot & 1);   // 0..15; 2 pairs per XCD (weights L2-pinned)
    const int bg   = slot >> 1;              // 0..15; barrier group
    const int b0   = bg * 4;

    const int jA0 = 32 * pair,        QA = 8 * pair,        CA = 256 - 8 * pair;
    const int jB0 = 32 * (31 - pair), QB = 248 - 8 * pair,  CB = 8 * pair + 8;
    const int QPHA = (CA + 15) >> 4;
    const int QPHB = (CB + 15) >> 4;
    const int kq0 = QA;                      // staged quad origin
    const int nq  = 256 - 8 * pair;          // real staged quads

    const int jA = jA0 + (tid & 31), jB = jB0 + (tid & 31);
    const float bo = bout[0];
    const float cA_bir = bir[jA], cA_bhr = bhr[jA], cA_biz = biz[jA], cA_bhz = bhz[jA];
    const float cA_bin = bin_[jA], cA_bhn = bhn[jA], cA_wo = Wout[jA];
    const float cB_bir = bir[jB], cB_bhr = bhr[jB], cB_biz = biz[jB], cB_bhz = bhz[jB];
    const float cB_bin = bin_[jB], cB_bhn = bhn[jB], cB_wo = Wout[jB];

    const float4* Wv4 = (const float4*)Wv;
    unsigned* mybar = barc + bg * 64;

    // zero all of sxh once: pad rows (>= nq) must stay zero
    for (int i = tid; i < NQP * 9; i += 512) ((float4*)sxh)[i] = make_float4(0.f, 0.f, 0.f, 0.f);
    __syncthreads();

    for (int t = 0; t < T_DIM; ++t) {
        const float* hid  = hbuf + (size_t)(t & 1) * (B_DIM * H_DIM);
        float*       hidn = hbuf + (size_t)((t + 1) & 1) * (B_DIM * H_DIM);
        const float* xt   = x + (size_t)t * (B_DIM * H_DIM);

        // ---- stage x,h (4 rows each) into quad-major layout ----
        {
            const int c = tid >> 6;                       // 0..7
            const int b = b0 + (c & 3);
            if (c < 4) {
                const float* src = xt + (size_t)b * H_DIM;
                #pragma unroll
                for (int r = 0; r < 4; ++r) {
                    const int kq = (tid & 63) + (r << 6);
                    if (kq < nq)
                        sxh[kq][c] = *(const float4*)(src + 4 * (kq0 + kq));
                }
            } else {
                float* src = (float*)hid + (size_t)b * H_DIM;
                #pragma unroll
                for (int r = 0; r < 4; ++r) {
                    const int kq = (tid & 63) + (r << 6);
                    if (kq < nq) {
                        float* s4 = src + 4 * (kq0 + kq);
                        float4 v;   // agent-scope loads: read h at the coherence point
                        v.x = __hip_atomic_load(s4 + 0, __ATOMIC_RELAXED, __HIP_MEMORY_SCOPE_AGENT);
                        v.y = __hip_atomic_load(s4 + 1, __ATOMIC_RELAXED, __HIP_MEMORY_SCOPE_AGENT);
                        v.z = __hip_atomic_load(s4 + 2, __ATOMIC_RELAXED, __HIP_MEMORY_SCOPE_AGENT);
                        v.w = __hip_atomic_load(s4 + 3, __ATOMIC_RELAXED, __HIP_MEMORY_SCOPE_AGENT);
                        sxh[kq][c] = v;
                    }
                }
            }
        }
        __syncthreads();

        #pragma unroll
        for (int bl = 0; bl < 2; ++bl) {
            const int j0  = bl ? jB0 : jA0;
            const int Qs  = bl ? QB : QA;
            const int QPH = bl ? QPHB : QPHA;
            const int qb  = Qs + 2 * ww * QPH;

            const float4* g0 = Wv4 + 0 * GSTR + j0 + jl;
            const float4* g1 = Wv4 + 1 * GSTR + j0 + jl;
            const float4* g2 = Wv4 + 2 * GSTR + j0 + jl;
            const float4* g3 = Wv4 + 3 * GSTR + j0 + jl;
            const float4* g4 = Wv4 + 4 * GSTR + j0 + jl;
            const float4* g5 = Wv4 + 5 * GSTR + j0 + jl;

            float4 acc[4];
            #pragma unroll
            for (int i = 0; i < 4; ++i) acc[i] = make_float4(0.f, 0.f, 0.f, 0.f);

            size_t qi = (size_t)(qb + sk) * H_DIM;
            int row = qb + sk - kq0;
            float4 cw0 = g0[qi], cw1 = g1[qi], cw2 = g2[qi],
                   cw3 = g3[qi], cw4 = g4[qi], cw5 = g5[qi];

            for (int iq = 0; iq < QPH; ++iq) {
                const size_t qn = qi + 2 * H_DIM;         // prefetch next (pad-safe)
                const float4 nw0 = g0[qn], nw1 = g1[qn], nw2 = g2[qn],
                             nw3 = g3[qn], nw4 = g4[qn], nw5 = g5[qn];
                #pragma unroll
                for (int b = 0; b < 4; ++b) {
                    const float4 xv = sxh[row][b];
                    const float4 hv = sxh[row][4 + b];
#define ACC(c) \
                    acc[b].x = fmaf(xv.c, cw0.c, fmaf(hv.c, cw3.c, acc[b].x)); \
                    acc[b].y = fmaf(xv.c, cw1.c, fmaf(hv.c, cw4.c, acc[b].y)); \
                    acc[b].z = fmaf(xv.c, cw2.c, acc[b].z); \
                    acc[b].w = fmaf(hv.c, cw5.c, acc[b].w);
                    ACC(x) ACC(y) ACC(z) ACC(w)
#undef ACC
                }
                cw0 = nw0; cw1 = nw1; cw2 = nw2; cw3 = nw3; cw4 = nw4; cw5 = nw5;
                qi = qn; row += 2;
            }

            #pragma unroll
            for (int b = 0; b < 4; ++b) {
                acc[b].x += __shfl_xor(acc[b].x, 32);
                acc[b].y += __shfl_xor(acc[b].y, 32);
                acc[b].z += __shfl_xor(acc[b].z, 32);
                acc[b].w += __shfl_xor(acc[b].w, 32);
            }
            if (lane < 32) {
                #pragma unroll
                for (int b = 0; b < 4; ++b) red[ww][b][jl] = acc[b];
            }
            __syncthreads();

            if (tid < 128) {
                const int b   = tid >> 5;
                const int jl2 = tid & 31;
                const int j   = j0 + jl2;
                float4 s = red[0][b][jl2];
                #pragma unroll
                for (int w2 = 1; w2 < 8; ++w2) {
                    const float4 v = red[w2][b][jl2];
                    s.x += v.x; s.y += v.y; s.z += v.z; s.w += v.w;
                }
                const int rr = bl ? (248 - 16 * pair + (jl2 >> 2)) : (jl2 >> 2);
                const float4 xq = sxh[rr][b];
                const float4 hq = sxh[rr][4 + b];
                const float xv = ((const float*)&xq)[jl2 & 3];
                const float hv = ((const float*)&hq)[jl2 & 3];
                const float v_bir = bl ? cB_bir : cA_bir, v_bhr = bl ? cB_bhr : cA_bhr;
                const float v_biz = bl ? cB_biz : cA_biz, v_bhz = bl ? cB_bhz : cA_bhz;
                const float v_bin = bl ? cB_bin : cA_bin, v_bhn = bl ? cB_bhn : cA_bhn;
                const float v_wo  = bl ? cB_wo  : cA_wo;
                const float rp = s.x + v_bir * xv + v_bhr;
                const float zp = s.y + v_biz * xv + v_bhz;
                const float r  = 1.0f / (1.0f + expf(-rp));
                const float z  = 1.0f / (1.0f + expf(-zp));
                const float np = s.z + v_bin * xv + r * (s.w + v_bhn);
                const float n  = tanhf(np);
                const float hnew = hv * z + (1.0f - z) * n;
                // agent-scope write-through: visible at coherence point before barrier arrival
                __hip_atomic_store(&hidn[(size_t)(b0 + b) * H_DIM + j], hnew,
                                   __ATOMIC_RELAXED, __HIP_MEMORY_SCOPE_AGENT);
                float lab = (1.0f / (1.0f + expf(-(hnew * v_wo + bo)))) * xv;
                #pragma unroll
                for (int off = 16; off; off >>= 1)
                    lab = fmaxf(lab, __shfl_xor(lab, off));
                if ((tid & 31) == 0) mxs[b][bl] = lab;
            }
            __syncthreads();
        }

        if (tid < 4)
            pmax[((size_t)t * B_DIM + b0 + tid) * 16 + pair] = fmaxf(mxs[tid][0], mxs[tid][1]);

        // ---- per-bgroup 16-WG monotone barrier (release RMW, relaxed spin) ----
        __syncthreads();
        if (tid == 0) {
            __hip_atomic_fetch_add(mybar, 1u, __ATOMIC_RELEASE, __HIP_MEMORY_SCOPE_AGENT);
            const unsigned tgt = 16u * (unsigned)(t + 1);
            while (__hip_atomic_load(mybar, __ATOMIC_RELAXED, __HIP_MEMORY_SCOPE_AGENT) < tgt)
                __builtin_amdgcn_s_sleep(2);
        }
        __syncthreads();
    }
}

// ---------------- finalize ----------------
__global__ __launch_bounds__(256) void finalize(const float* __restrict__ pmax, int* __restrict__ out)
{
    const int i = blockIdx.x * 256 + threadIdx.x; // 0..T*B-1
    if (i >= T_DIM * B_DIM) return;
    const float4* pm = (const float4*)(pmax + (size_t)i * 16);
    float m = -3.4e38f;
    #pragma unroll
    for (int q = 0; q < 4; ++q) {
        const float4 v = pm[q];
        m = fmaxf(m, fmaxf(fmaxf(v.x, v.y), fmaxf(v.z, v.w)));
    }
    out[i] = (m >= 0.5f) ? 1 : -1;
}

extern "C" void kernel_launch(void* const* d_in, const int* in_sizes, int n_in,
                              void* d_out, int out_size, void* d_ws, size_t ws_size,
                              hipStream_t stream)
{
    const float* x    = (const float*)d_in[0];
    const float* h0   = (const float*)d_in[1];
    const float* W_ir = (const float*)d_in[2];
    const float* W_hr = (const float*)d_in[3];
    const float* W_iz = (const float*)d_in[4];
    const float* W_hz = (const float*)d_in[5];
    const float* W_in = (const float*)d_in[6];
    const float* W_hn = (const float*)d_in[7];
    const float* b_ir = (const float*)d_in[8];
    const float* b_hr = (const float*)d_in[9];
    const float* b_iz = (const float*)d_in[10];
    const float* b_hz = (const float*)d_in[11];
    const float* b_in = (const float*)d_in[12];
    const float* b_hn = (const float*)d_in[13];
    const float* W_out = (const float*)d_in[14];
    const float* b_out = (const float*)d_in[15];

    float* ws   = (float*)d_ws;
    float* Wv   = ws;                                        // 6*NQP*H*4 floats (~26.7 MB)
    float* hbuf = Wv + (size_t)6 * NQP * H_DIM * 4;          // 2*B*H
    float* pmax = hbuf + (size_t)2 * B_DIM * H_DIM;          // T*B*16 (2 MB)
    unsigned* barc = (unsigned*)(pmax + (size_t)T_DIM * B_DIM * 16); // 16*64 uints

    prep_interleave<<<dim3(NQP, 4, 6), 256, 0, stream>>>(W_ir, W_iz, W_in, W_hr, W_hz, W_hn, Wv);
    init_h<<<dim3(257), 256, 0, stream>>>(h0, hbuf, barc);

    void* args[] = {(void*)&x, (void*)&Wv,
                    (void*)&b_ir, (void*)&b_hr, (void*)&b_iz, (void*)&b_hz,
                    (void*)&b_in, (void*)&b_hn, (void*)&W_out, (void*)&b_out,
                    (void*)&hbuf, (void*)&pmax, (void*)&barc};
    // dynamic LDS pads group segment >80 KB -> exactly 1 WG/CU placement
    hipLaunchCooperativeKernel((const void*)gru_main, dim3(256), dim3(512), args, 40960, stream);

    finalize<<<dim3(T_DIM * B_DIM / 256), 256, 0, stream>>>(pmax, (int*)d_out);
}